// Round 8
// baseline (152.564 us; speedup 1.0000x reference)
//
#include <hip/hip_runtime.h>

#define DIM 64
#define NVOX (DIM * DIM * DIM)
#define NFACES 304          // per field: 96 x-faces + 96 y-faces + 112 z-faces
#define MAGIC  0x5A5A5A5A   // != workspace poison 0xAAAAAAAA

// ---------------------------------------------------------------------------
// Lock-free union-find (ECL-CC style), works on global OR LDS int arrays.
// Invariant: every stored parent is a strictly-smaller-index ancestor ->
// stale (non-coherent L1) reads still see valid ancestors; atomicCAS is the
// coherent ground truth; failed CAS returns a strictly smaller value ->
// guaranteed termination.
// ---------------------------------------------------------------------------
__device__ __forceinline__ int find_root_link(int* L, int v) {
    for (;;) {
        int p = L[v];
        if (p == v) return v;
        int gp = L[p];
        if (gp == p) return p;
        L[v] = gp;   // path-halving: writes an ancestor, races benign
        v = gp;
    }
}

__device__ __forceinline__ void unite(int* L, int a, int b) {
    int ra = find_root_link(L, a);
    int rb = find_root_link(L, b);
    while (ra != rb) {
        if (ra > rb) { int t = ra; ra = rb; rb = t; }
        int old = atomicCAS(&L[rb], rb, ra);
        if (old == rb) break;            // hooked rb -> ra
        rb = find_root_link(L, old);     // old coherent, strictly < rb
        ra = find_root_link(L, ra);
    }
}

// read-only chase (no writes; valid ancestor even under concurrent unites)
__device__ __forceinline__ int chase(const int* __restrict__ L, int p) {
    int q = L[p];
    while (q != p) { p = q; q = L[p]; }
    return p;
}

// ---------------------------------------------------------------------------
// Phase 1+2 fused: per-tile LDS CCL (tile 16x16x8, grid 128 tiles x 2 fields)
// + cross-tile boundary unites via per-face arrival handshake.
// Each face (shared by exactly 2 tiles) is processed by the SECOND arriver:
//   writer: label stores -> __syncthreads (vmcnt0 drain) -> __threadfence
//           (agent-scope release) -> atomicExch(face, MAGIC)
//   second arriver sees old==MAGIC -> __threadfence (acquire) -> reads both
//   tiles' labels. Every face processed exactly once; no waiting -> no
//   deadlock. Chases only reach completed tiles (cross-tile parent pointers
//   are only ever installed between two completed tiles).
// fctr starts at harness poison 0xAAAAAAAA != MAGIC (re-poisoned per launch).
// ---------------------------------------------------------------------------
__global__ void __launch_bounds__(256)
local_link(const float* __restrict__ pred, const float* __restrict__ lab,
           int* __restrict__ LP, int* __restrict__ LL,
           int* __restrict__ fctr, float* __restrict__ out) {
    __shared__ int s_lab[2048];
    __shared__ int s_face[6];
    int t = threadIdx.x;
    int b = blockIdx.x, f = blockIdx.y;
    if (b == 0 && f == 0 && t == 0) *out = 0.0f;   // replaces memset dispatch

    int tx = b & 3, ty = (b >> 2) & 3, tz = b >> 4;   // 4 x 4 x 8 tiles
    int X0 = tx << 4, Y0 = ty << 4, Z0 = tz << 3;
    const float* src = f ? lab : pred;
    int* Lg = f ? LL : LP;

    bool fg[8];
    int vv[8];
#pragma unroll
    for (int i = 0; i < 8; ++i) {
        int l = t + (i << 8);                    // lx=l&15, ly=(l>>4)&15, lz=l>>8
        int v = ((Z0 + (l >> 8)) << 12) | ((Y0 + ((l >> 4) & 15)) << 6)
              | (X0 + (l & 15));
        vv[i] = v;
        fg[i] = src[v] > 0.0f;
        s_lab[l] = fg[i] ? l : -1;
    }
    __syncthreads();

#pragma unroll
    for (int i = 0; i < 8; ++i) {
        if (!fg[i]) continue;
        int l = t + (i << 8);
        int lx = l & 15, ly = (l >> 4) & 15, lz = l >> 8;
        if (lx < 15 && s_lab[l + 1]   >= 0) unite(s_lab, l, l + 1);
        if (ly < 15 && s_lab[l + 16]  >= 0) unite(s_lab, l, l + 16);
        if (lz < 7  && s_lab[l + 256] >= 0) unite(s_lab, l, l + 256);
    }
    __syncthreads();

#pragma unroll
    for (int i = 0; i < 8; ++i) {
        int g = -1;
        if (fg[i]) {
            int p = s_lab[t + (i << 8)];
            while (s_lab[p] != p) p = s_lab[p];  // read-only chase
            g = ((Z0 + (p >> 8)) << 12) | ((Y0 + ((p >> 4) & 15)) << 6)
              | (X0 + (p & 15));                 // monotone: g <= v
        }
        Lg[vv[i]] = g;
    }
    __syncthreads();     // all tile label stores drained (vmcnt0 at barrier)
    __threadfence();     // release: visible at device-coherent point

    // ---- handshake: dirs 0:-x 1:+x 2:-y 3:+y 4:-z 5:+z ----
    if (t < 6) {
        int face = -1;
        if      (t == 0 && tx > 0) face = (tz * 4 + ty) * 3 + (tx - 1);
        else if (t == 1 && tx < 3) face = (tz * 4 + ty) * 3 + tx;
        else if (t == 2 && ty > 0) face = 96 + (tz * 4 + tx) * 3 + (ty - 1);
        else if (t == 3 && ty < 3) face = 96 + (tz * 4 + tx) * 3 + ty;
        else if (t == 4 && tz > 0) face = 192 + (ty * 4 + tx) * 7 + (tz - 1);
        else if (t == 5 && tz < 7) face = 192 + (ty * 4 + tx) * 7 + tz;
        int proc = -1;
        if (face >= 0) {
            int old = atomicExch(&fctr[f * NFACES + face], MAGIC);
            if (old == MAGIC) proc = face;       // we are second: both sides ready
        }
        s_face[t] = proc;
    }
    __syncthreads();
    __threadfence();     // acquire: discard stale cached lines before reads

    for (int s = 0; s < 6; ++s) {
        int face = s_face[s];
        if (face < 0) continue;
        int v = -1, n = -1;
        if (face < 96) {                          // x-face: 16y x 8z = 128 edges
            if (t < 128) {
                int txm = face % 3, r = face / 3;
                int y = ((r & 3) << 4) | (t & 15);      // lane-consecutive: dedupe runs
                int z = ((r >> 2) << 3) | (t >> 4);
                v = (z << 12) | (y << 6) | ((txm << 4) | 15);
                n = v + 1;
            }
        } else if (face < 192) {                  // y-face: 16x x 8z = 128 edges
            if (t < 128) {
                int g2 = face - 96;
                int tym = g2 % 3, r = g2 / 3;
                int x = ((r & 3) << 4) | (t & 15);
                int z = ((r >> 2) << 3) | (t >> 4);
                v = (z << 12) | (((tym << 4) | 15) << 6) | x;
                n = v + 64;
            }
        } else {                                  // z-face: 16x x 16y = 256 edges
            int g2 = face - 192;
            int tzm = g2 % 7, r = g2 / 7;
            int x = ((r & 3) << 4) | (t & 15);
            int y = ((r >> 2) << 4) | ((t >> 4) & 15);
            v = (((tzm << 3) | 7) << 12) | (y << 6) | x;
            n = v + 4096;
        }
        int r0 = -1, r1 = -1;
        if (v >= 0) {
            int a = Lg[v], c = Lg[n];
            if (a >= 0 && c >= 0) {
                int u0 = chase(Lg, a), u1 = chase(Lg, c);
                r0 = min(u0, u1); r1 = max(u0, u1);
            }
        }
        // wave-level dedupe: runs of identical root pairs -> single unite
        int lane = t & 63;
        int q0 = __shfl_up(r0, 1, 64), q1 = __shfl_up(r1, 1, 64);
        bool dup = lane && (q0 == r0) && (q1 == r1);
        if (r0 >= 0 && r0 != r1 && !dup) unite(Lg, r0, r1);
    }
}

// ---------------------------------------------------------------------------
// 27-bit 3x3x3 mask connectivity via branch-free separable dilation.
// Bit index = z*9 + y*3 + x.
// ---------------------------------------------------------------------------
#define MX_L 0x6DB6DB6u   // result x in {1,2}
#define MX_R 0x36DB6DBu   // result x in {0,1}
#define MY_L 0x7E3F1F8u   // result y in {1,2}
#define MY_R 0x0FC7E3Fu   // result y in {0,1}
#define M27  0x7FFFFFFu

__device__ __forceinline__ unsigned dil26(unsigned m) {
    m |= ((m << 1) & MX_L) | ((m >> 1) & MX_R);
    m |= ((m << 3) & MY_L) | ((m >> 3) & MY_R);
    m |= ((m << 9) & M27)  | (m >> 9);
    return m;
}
__device__ __forceinline__ unsigned dil18(unsigned m) {
    unsigned ax = m | ((m << 1) & MX_L) | ((m >> 1) & MX_R);    // Dx
    unsigned ay = m | ((m << 3) & MY_L) | ((m >> 3) & MY_R);    // Dy
    unsigned dxy = ax | ((ax << 3) & MY_L) | ((ax >> 3) & MY_R);      // DyDx
    unsigned dxz = ax | ((ax << 9) & M27)  | (ax >> 9);               // DzDx
    unsigned dyz = ay | ((ay << 9) & M27)  | (ay >> 9);               // DzDy
    return dxy | dxz | dyz;   // all offsets with >=1 zero component
}

__device__ __forceinline__ bool single18(unsigned m) {
    if (!m) return false;
    unsigned c = m & (~m + 1u);
    for (;;) {
        unsigned n = dil18(c) & m;
        if (n == m) return true;
        if (n == c) return false;
        c = n;
    }
}
__device__ __forceinline__ bool single26(unsigned m) {
    if (!m) return false;
    unsigned c = m & (~m + 1u);
    for (;;) {
        unsigned n = dil26(c) & m;
        if (n == m) return true;
        if (n == c) return false;
        c = n;
    }
}

// ---------------------------------------------------------------------------
// Phase 3: non-simple maps + weighted BCE + mean. Halo loads chase labels to
// their final roots (no compress pass; read-only, exact).
// Tile 8x8x4, block 256, grid 1024. Halo 10x10x6 per field.
// ---------------------------------------------------------------------------
#define HV 600   // 10*10*6

__global__ void finalize_kernel(const float* __restrict__ pred,
                                const float* __restrict__ lab,
                                const int* __restrict__ LP,
                                const int* __restrict__ LL,
                                float* __restrict__ out) {
    __shared__ int sP[HV], sL[HV];
    __shared__ float s_part[4];
    int t = threadIdx.x;
    int b = blockIdx.x;                          // 8 x 8 x 16 tiles
    int tx = b & 7, ty = (b >> 3) & 7, tz = b >> 6;
    int x0 = tx << 3, y0 = ty << 3, z0 = tz << 2;

    for (int i = t; i < HV; i += 256) {
        int hx = i % 10, r = i / 10, hy = r % 10, hz = r / 10;
        int gx = x0 + hx - 1; gx = gx < 0 ? 0 : (gx > 63 ? 63 : gx);  // edge pad
        int gy = y0 + hy - 1; gy = gy < 0 ? 0 : (gy > 63 ? 63 : gy);
        int gz = z0 + hz - 1; gz = gz < 0 ? 0 : (gz > 63 ? 63 : gz);
        int gv = (gz << 12) | (gy << 6) | gx;
        int p = LP[gv];
        if (p >= 0) p = chase(LP, p);
        sP[i] = p;
        p = LL[gv];
        if (p >= 0) p = chase(LL, p);
        sL[i] = p;
    }
    __syncthreads();

    // tile 8x8x4: lx = bits[0:3), ly = bits[3:6), lz = bits[6:8)
    int lx = t & 7, ly = (t >> 3) & 7, lz = t >> 6;
    int x = x0 | lx, y = y0 | ly, z = z0 | lz;
    int v = (z << 12) | (y << 6) | x;
    int base = lz * 100 + ly * 10 + lx;          // halo idx of (-1,-1,-1) corner

    bool nsP = false, nsL = false;
    {
        int c = sP[base + 111];                  // center
        if (c >= 0) {
            unsigned m1 = 0, m2 = 0; int k = 0;
#pragma unroll
            for (int kz = 0; kz < 3; ++kz)
#pragma unroll
                for (int ky = 0; ky < 3; ++ky)
#pragma unroll
                    for (int kx = 0; kx < 3; ++kx, ++k) {
                        int w = sP[base + kz * 100 + ky * 10 + kx];
                        m1 |= (unsigned)(w != c) << k;
                        m2 |= (unsigned)(w == c) << k;
                    }
            m2 &= ~(1u << 13);                   // drop center
            nsP = !(single18(m1) && single26(m2));
        }
    }
    {
        int c = sL[base + 111];
        if (c >= 0) {
            unsigned m1 = 0, m2 = 0; int k = 0;
#pragma unroll
            for (int kz = 0; kz < 3; ++kz)
#pragma unroll
                for (int ky = 0; ky < 3; ++ky)
#pragma unroll
                    for (int kx = 0; kx < 3; ++kx, ++k) {
                        int w = sL[base + kz * 100 + ky * 10 + kx];
                        m1 |= (unsigned)(w != c) << k;
                        m2 |= (unsigned)(w == c) << k;
                    }
            m2 &= ~(1u << 13);
            nsL = !(single18(m1) && single26(m2));
        }
    }

    float p = pred[v], l = lab[v];
    float cost = fmaxf(p, 0.0f) - p * l + log1pf(__expf(-fabsf(p)));
    float w = (nsP || nsL) ? 5.0f : 1.0f;
    float contrib = w * cost;

#pragma unroll
    for (int off = 32; off > 0; off >>= 1)
        contrib += __shfl_down(contrib, off, 64);
    if ((t & 63) == 0) s_part[t >> 6] = contrib;
    __syncthreads();
    if (t == 0) {
        float s = s_part[0] + s_part[1] + s_part[2] + s_part[3];
        atomicAdd(out, s * (1.0f / (float)NVOX));
    }
}

extern "C" void kernel_launch(void* const* d_in, const int* in_sizes, int n_in,
                              void* d_out, int out_size, void* d_ws, size_t ws_size,
                              hipStream_t stream) {
    const float* pred = (const float*)d_in[0];   // 'prediction'
    const float* lab  = (const float*)d_in[1];   // 'label'
    float* out = (float*)d_out;

    int* LP   = (int*)d_ws;          // NVOX ints
    int* LL   = LP + NVOX;           // NVOX ints
    int* fctr = LL + NVOX;           // 2*NFACES ints (harness poison = "empty")

    hipLaunchKernelGGL(local_link, dim3(128, 2), dim3(256), 0, stream,
                       pred, lab, LP, LL, fctr, out);
    hipLaunchKernelGGL(finalize_kernel, dim3(NVOX / 256), dim3(256), 0, stream,
                       pred, lab, LP, LL, out);
}

// Round 9
// 109.842 us; speedup vs baseline: 1.3889x; 1.3889x over previous
//
#include <hip/hip_runtime.h>

#define DIM 64
#define NVOX (DIM * DIM * DIM)
#define EPF 53248          // boundary edges per field

// ---------------------------------------------------------------------------
// Lock-free union-find (ECL-CC style), works on global OR LDS int arrays.
// Invariant: every stored parent is a strictly-smaller-index ancestor ->
// stale (non-coherent L1) reads still see valid ancestors; atomicCAS is the
// coherent ground truth; failed CAS returns a strictly smaller value ->
// guaranteed termination.
// ---------------------------------------------------------------------------
__device__ __forceinline__ int find_root_link(int* L, int v) {
    for (;;) {
        int p = L[v];
        if (p == v) return v;
        int gp = L[p];
        if (gp == p) return p;
        L[v] = gp;   // path-halving: writes an ancestor, races benign
        v = gp;
    }
}

__device__ __forceinline__ void unite(int* L, int a, int b) {
    int ra = find_root_link(L, a);
    int rb = find_root_link(L, b);
    while (ra != rb) {
        if (ra > rb) { int t = ra; ra = rb; rb = t; }
        int old = atomicCAS(&L[rb], rb, ra);
        if (old == rb) break;            // hooked rb -> ra
        rb = find_root_link(L, old);     // old coherent, strictly < rb
        ra = find_root_link(L, ra);
    }
}

// read-only chase (no writes; valid ancestor even under concurrent unites)
__device__ __forceinline__ int chase(const int* __restrict__ L, int p) {
    int q = L[p];
    while (q != p) { p = q; q = L[p]; }
    return p;
}

// ---------------------------------------------------------------------------
// Phase 1: per-tile CCL in LDS. Tile 16x16x8 = 2048 voxels, 256 threads
// (8 voxels/thread), grid (128 tiles, 2 fields) = 256 blocks -> full machine.
// Writes global label = global index of tile-local root (monotone map keeps
// parent <= child globally). Block (0,0) also zeroes d_out (ordered before
// finalize's atomics by the dispatch boundary).
// ---------------------------------------------------------------------------
__global__ void local_ccl(const float* __restrict__ pred,
                          const float* __restrict__ lab,
                          int* __restrict__ LP, int* __restrict__ LL,
                          float* __restrict__ out) {
    __shared__ int s_lab[2048];
    int t = threadIdx.x;
    if (blockIdx.x == 0 && blockIdx.y == 0 && t == 0) *out = 0.0f;
    int b = blockIdx.x;                         // 128 tiles: 4 x 4 x 8
    int tx = b & 3, ty = (b >> 2) & 3, tz = b >> 4;
    int X0 = tx << 4, Y0 = ty << 4, Z0 = tz << 3;

    const float* src = blockIdx.y ? lab : pred;
    int* Lg = blockIdx.y ? LL : LP;

    bool fg[8];
    int vv[8];
#pragma unroll
    for (int i = 0; i < 8; ++i) {
        int l = t + (i << 8);                   // lx=l&15, ly=(l>>4)&15, lz=l>>8
        int v = ((Z0 + (l >> 8)) << 12) | ((Y0 + ((l >> 4) & 15)) << 6)
              | (X0 + (l & 15));
        vv[i] = v;
        fg[i] = src[v] > 0.0f;
        s_lab[l] = fg[i] ? l : -1;
    }
    __syncthreads();

#pragma unroll
    for (int i = 0; i < 8; ++i) {
        if (!fg[i]) continue;
        int l = t + (i << 8);
        int lx = l & 15, ly = (l >> 4) & 15, lz = l >> 8;
        if (lx < 15 && s_lab[l + 1]   >= 0) unite(s_lab, l, l + 1);
        if (ly < 15 && s_lab[l + 16]  >= 0) unite(s_lab, l, l + 16);
        if (lz < 7  && s_lab[l + 256] >= 0) unite(s_lab, l, l + 256);
    }
    __syncthreads();

#pragma unroll
    for (int i = 0; i < 8; ++i) {
        int g = -1;
        if (fg[i]) {
            int p = s_lab[t + (i << 8)];
            while (s_lab[p] != p) p = s_lab[p];  // read-only chase
            g = ((Z0 + (p >> 8)) << 12) | ((Y0 + ((p >> 4) & 15)) << 6)
              | (X0 + (p & 15));
        }
        Lg[vv[i]] = g;
    }
}

// ---------------------------------------------------------------------------
// Phase 2: compact cross-tile edge list, one thread per geometric edge,
// both fields per thread.
// KEY CHANGE (R9): dedupe on the RAW tile-component pair BEFORE chasing --
// consecutive edges along a face mostly connect the same pair of local
// components (the percolating cluster), so the dependent global chase
// (the measured cost, ~24us) is skipped for run-duplicate lanes entirely.
// A second dedupe on final roots then skips redundant unites.
// Raw labels may be mid-halving values; any stored value is a valid ancestor,
// so a missed dedupe is only a tiny redundancy, never an error.
// ---------------------------------------------------------------------------
__global__ void boundary_link(int* __restrict__ LP, int* __restrict__ LL) {
    int r = blockIdx.x * blockDim.x + threadIdx.x;   // 0..EPF-1
    int v, n;
    if (r < 12288) {                             // x-faces: planes 15,31,47
        int plane = 15 + ((r >> 12) << 4);
        int ij = r & 4095;                       // y = ij&63 (lane-consecutive), z = ij>>6
        v = ((ij >> 6) << 12) | ((ij & 63) << 6) | plane;
        n = v + 1;
    } else if (r < 24576) {                      // y-faces: planes 15,31,47
        int r2 = r - 12288;
        int plane = 15 + ((r2 >> 12) << 4);
        int ij = r2 & 4095;                      // x = ij&63, z = ij>>6
        v = ((ij >> 6) << 12) | (plane << 6) | (ij & 63);
        n = v + 64;
    } else {                                     // z-faces: planes 7..55
        int r3 = r - 24576;
        int plane = 7 + ((r3 >> 12) << 3);
        int ij = r3 & 4095;                      // x = ij&63, y = ij>>6
        v = (plane << 12) | ((ij >> 6) << 6) | (ij & 63);
        n = v + 4096;
    }

    int lane = threadIdx.x & 63;

    int pa = LP[v], pb = LP[n];
    int la = LL[v], lb = LL[n];
    bool doP = (pa >= 0) & (pb >= 0);
    bool doL = (la >= 0) & (lb >= 0);

    // raw-pair dedupe (kills the chase for run-duplicates)
    int xpa = __shfl_up(pa, 1, 64), xpb = __shfl_up(pb, 1, 64);
    int xla = __shfl_up(la, 1, 64), xlb = __shfl_up(lb, 1, 64);
    if (lane && xpa == pa && xpb == pb) doP = false;
    if (lane && xla == la && xlb == lb) doL = false;

    int rp0 = -1, rp1 = -1, rl0 = -1, rl1 = -1;
    if (doP) {
        int u0 = chase(LP, pa), u1 = chase(LP, pb);
        rp0 = min(u0, u1); rp1 = max(u0, u1);
    }
    if (doL) {
        int u0 = chase(LL, la), u1 = chase(LL, lb);
        rl0 = min(u0, u1); rl1 = max(u0, u1);
    }

    // root-pair dedupe (different raw pairs may share final roots)
    int qp0 = __shfl_up(rp0, 1, 64), qp1 = __shfl_up(rp1, 1, 64);
    int ql0 = __shfl_up(rl0, 1, 64), ql1 = __shfl_up(rl1, 1, 64);
    bool dupP = lane && (qp0 == rp0) && (qp1 == rp1);
    bool dupL = lane && (ql0 == rl0) && (ql1 == rl1);

    if (rp0 >= 0 && rp0 != rp1 && !dupP) unite(LP, rp0, rp1);
    if (rl0 >= 0 && rl0 != rl1 && !dupL) unite(LL, rl0, rl1);
}

// ---------------------------------------------------------------------------
// 27-bit 3x3x3 mask connectivity via branch-free separable dilation.
// Bit index = z*9 + y*3 + x.
// ---------------------------------------------------------------------------
#define MX_L 0x6DB6DB6u   // result x in {1,2}
#define MX_R 0x36DB6DBu   // result x in {0,1}
#define MY_L 0x7E3F1F8u   // result y in {1,2}
#define MY_R 0x0FC7E3Fu   // result y in {0,1}
#define M27  0x7FFFFFFu

__device__ __forceinline__ unsigned dil26(unsigned m) {
    m |= ((m << 1) & MX_L) | ((m >> 1) & MX_R);
    m |= ((m << 3) & MY_L) | ((m >> 3) & MY_R);
    m |= ((m << 9) & M27)  | (m >> 9);
    return m;
}
__device__ __forceinline__ unsigned dil18(unsigned m) {
    unsigned ax = m | ((m << 1) & MX_L) | ((m >> 1) & MX_R);    // Dx
    unsigned ay = m | ((m << 3) & MY_L) | ((m >> 3) & MY_R);    // Dy
    unsigned dxy = ax | ((ax << 3) & MY_L) | ((ax >> 3) & MY_R);      // DyDx
    unsigned dxz = ax | ((ax << 9) & M27)  | (ax >> 9);               // DzDx
    unsigned dyz = ay | ((ay << 9) & M27)  | (ay >> 9);               // DzDy
    return dxy | dxz | dyz;   // all offsets with >=1 zero component
}

__device__ __forceinline__ bool single18(unsigned m) {
    if (!m) return false;
    unsigned c = m & (~m + 1u);
    for (;;) {
        unsigned n = dil18(c) & m;
        if (n == m) return true;
        if (n == c) return false;
        c = n;
    }
}
__device__ __forceinline__ bool single26(unsigned m) {
    if (!m) return false;
    unsigned c = m & (~m + 1u);
    for (;;) {
        unsigned n = dil26(c) & m;
        if (n == m) return true;
        if (n == c) return false;
        c = n;
    }
}

// ---------------------------------------------------------------------------
// Phase 3: non-simple maps + weighted BCE + mean.
// R9: region 8x8x8 per block (512 blocks, 2 voxels/thread), halo 10x10x10
// per field (ratio 1.95x vs 2.34x before). Halo loads are batched (all
// independent loads issued, then the dependent chases) for latency hiding.
// Halo layout: i = hz*100 + hy*10 + hx; window corner of (lx,ly,lz) = base,
// center = base + 111.
// ---------------------------------------------------------------------------
#define HV 1000   // 10*10*10

__global__ void finalize_kernel(const float* __restrict__ pred,
                                const float* __restrict__ lab,
                                const int* __restrict__ LP,
                                const int* __restrict__ LL,
                                float* __restrict__ out) {
    __shared__ int sP[HV], sL[HV];
    __shared__ float s_part[4];
    int t = threadIdx.x;
    int b = blockIdx.x;                          // 8 x 8 x 8 regions
    int rx = b & 7, ry = (b >> 3) & 7, rz = b >> 6;
    int x0 = rx << 3, y0 = ry << 3, z0 = rz << 3;

    // batched halo load: issue all independent loads first, then chase
    int pv[4], lv[4];
#pragma unroll
    for (int j = 0; j < 4; ++j) {
        int i = t + (j << 8);
        if (i < HV) {
            int hx = i % 10, rr = i / 10, hy = rr % 10, hz = rr / 10;
            int gx = x0 + hx - 1; gx = gx < 0 ? 0 : (gx > 63 ? 63 : gx);
            int gy = y0 + hy - 1; gy = gy < 0 ? 0 : (gy > 63 ? 63 : gy);
            int gz = z0 + hz - 1; gz = gz < 0 ? 0 : (gz > 63 ? 63 : gz);
            int gv = (gz << 12) | (gy << 6) | gx;
            pv[j] = LP[gv];
            lv[j] = LL[gv];
        }
    }
#pragma unroll
    for (int j = 0; j < 4; ++j) {
        int i = t + (j << 8);
        if (i < HV) {
            int p = pv[j];
            if (p >= 0) p = chase(LP, p);
            sP[i] = p;
            p = lv[j];
            if (p >= 0) p = chase(LL, p);
            sL[i] = p;
        }
    }
    __syncthreads();

    float acc = 0.0f;
#pragma unroll
    for (int j = 0; j < 2; ++j) {
        int l = t + (j << 8);                    // region 8x8x8: 512 voxels
        int lx = l & 7, ly = (l >> 3) & 7, lz = l >> 6;
        int x = x0 | lx, y = y0 | ly, z = z0 | lz;
        int v = (z << 12) | (y << 6) | x;
        int base = lz * 100 + ly * 10 + lx;      // (-1,-1,-1) corner

        bool nsP = false, nsL = false;
        {
            int c = sP[base + 111];              // center
            if (c >= 0) {
                unsigned m1 = 0, m2 = 0; int k = 0;
#pragma unroll
                for (int kz = 0; kz < 3; ++kz)
#pragma unroll
                    for (int ky = 0; ky < 3; ++ky)
#pragma unroll
                        for (int kx = 0; kx < 3; ++kx, ++k) {
                            int w = sP[base + kz * 100 + ky * 10 + kx];
                            m1 |= (unsigned)(w != c) << k;
                            m2 |= (unsigned)(w == c) << k;
                        }
                m2 &= ~(1u << 13);               // drop center
                nsP = !(single18(m1) && single26(m2));
            }
        }
        {
            int c = sL[base + 111];
            if (c >= 0) {
                unsigned m1 = 0, m2 = 0; int k = 0;
#pragma unroll
                for (int kz = 0; kz < 3; ++kz)
#pragma unroll
                    for (int ky = 0; ky < 3; ++ky)
#pragma unroll
                        for (int kx = 0; kx < 3; ++kx, ++k) {
                            int w = sL[base + kz * 100 + ky * 10 + kx];
                            m1 |= (unsigned)(w != c) << k;
                            m2 |= (unsigned)(w == c) << k;
                        }
                m2 &= ~(1u << 13);
                nsL = !(single18(m1) && single26(m2));
            }
        }

        float p = pred[v], lvf = lab[v];
        float cost = fmaxf(p, 0.0f) - p * lvf + log1pf(__expf(-fabsf(p)));
        acc += ((nsP || nsL) ? 5.0f : 1.0f) * cost;
    }

#pragma unroll
    for (int off = 32; off > 0; off >>= 1)
        acc += __shfl_down(acc, off, 64);
    if ((t & 63) == 0) s_part[t >> 6] = acc;
    __syncthreads();
    if (t == 0) {
        float s = s_part[0] + s_part[1] + s_part[2] + s_part[3];
        atomicAdd(out, s * (1.0f / (float)NVOX));
    }
}

extern "C" void kernel_launch(void* const* d_in, const int* in_sizes, int n_in,
                              void* d_out, int out_size, void* d_ws, size_t ws_size,
                              hipStream_t stream) {
    const float* pred = (const float*)d_in[0];   // 'prediction'
    const float* lab  = (const float*)d_in[1];   // 'label'
    float* out = (float*)d_out;

    int* LP = (int*)d_ws;          // NVOX ints
    int* LL = LP + NVOX;           // NVOX ints  (2 MiB total)

    hipLaunchKernelGGL(local_ccl, dim3(128, 2), dim3(256), 0, stream,
                       pred, lab, LP, LL, out);
    hipLaunchKernelGGL(boundary_link, dim3(EPF / 256), dim3(256), 0, stream,
                       LP, LL);
    hipLaunchKernelGGL(finalize_kernel, dim3(512), dim3(256), 0, stream,
                       pred, lab, LP, LL, out);
}